// Round 1
// baseline (1311.881 us; speedup 1.0000x reference)
//
#include <hip/hip_runtime.h>
#include <hip/hip_bf16.h>
#include <cstdint>
#include <cmath>

#define NN 4096
#define FF 512
#define HH 64

// ---------------- threefry2x32 (JAX-compatible, 20 rounds) ----------------
__host__ __device__ __forceinline__ uint32_t rotl32(uint32_t x, int r) {
    return (x << r) | (x >> (32 - r));
}

__host__ __device__ __forceinline__ void threefry2x32(uint32_t ks0, uint32_t ks1,
                                                      uint32_t x0, uint32_t x1,
                                                      uint32_t& o0, uint32_t& o1) {
    uint32_t ks2 = ks0 ^ ks1 ^ 0x1BD11BDAu;
    x0 += ks0; x1 += ks1;
    x0 += x1; x1 = rotl32(x1, 13); x1 ^= x0;
    x0 += x1; x1 = rotl32(x1, 15); x1 ^= x0;
    x0 += x1; x1 = rotl32(x1, 26); x1 ^= x0;
    x0 += x1; x1 = rotl32(x1,  6); x1 ^= x0;
    x0 += ks1; x1 += ks2 + 1u;
    x0 += x1; x1 = rotl32(x1, 17); x1 ^= x0;
    x0 += x1; x1 = rotl32(x1, 29); x1 ^= x0;
    x0 += x1; x1 = rotl32(x1, 16); x1 ^= x0;
    x0 += x1; x1 = rotl32(x1, 24); x1 ^= x0;
    x0 += ks2; x1 += ks0 + 2u;
    x0 += x1; x1 = rotl32(x1, 13); x1 ^= x0;
    x0 += x1; x1 = rotl32(x1, 15); x1 ^= x0;
    x0 += x1; x1 = rotl32(x1, 26); x1 ^= x0;
    x0 += x1; x1 = rotl32(x1,  6); x1 ^= x0;
    x0 += ks0; x1 += ks1 + 3u;
    x0 += x1; x1 = rotl32(x1, 17); x1 ^= x0;
    x0 += x1; x1 = rotl32(x1, 29); x1 ^= x0;
    x0 += x1; x1 = rotl32(x1, 16); x1 ^= x0;
    x0 += x1; x1 = rotl32(x1, 24); x1 ^= x0;
    x0 += ks1; x1 += ks2 + 4u;
    x0 += x1; x1 = rotl32(x1, 13); x1 ^= x0;
    x0 += x1; x1 = rotl32(x1, 15); x1 ^= x0;
    x0 += x1; x1 = rotl32(x1, 26); x1 ^= x0;
    x0 += x1; x1 = rotl32(x1,  6); x1 ^= x0;
    x0 += ks2; x1 += ks0 + 5u;
    o0 = x0; o1 = x1;
}

// partitionable 32-bit random bits for flat index j (hi word of 64-bit iota = 0)
__device__ __forceinline__ uint32_t jax_bits32(uint32_t k0, uint32_t k1, uint32_t j) {
    uint32_t b0, b1;
    threefry2x32(k0, k1, 0u, j, b0, b1);
    return b0 ^ b1;
}

// jax.random.uniform(float32, minval=1e-6, maxval=1-1e-6) from raw bits.
// NOTE: __fmul_rn/__fadd_rn prevent FMA contraction (XLA/numpy do separate mul+add).
__device__ __forceinline__ float jax_uniform(uint32_t bits) {
    const float minv = 1e-6f;
    const float maxv = (float)(1.0 - 1e-6);
    const float span = maxv - minv;  // constant-folded in f32 RN
    float f = __uint_as_float((bits >> 9) | 0x3f800000u) - 1.0f;
    float u = __fadd_rn(__fmul_rn(f, span), minv);
    return fmaxf(minv, u);
}

// hard Bernoulli-ST forward: 1[ l + logit(u) > 0 ]  <=>  u > 1/(1+e^l)
__device__ __forceinline__ float hard_sample(double l, float u32) {
    double thr = 1.0 / (1.0 + exp(l));
    return ((double)u32 > thr) ? 1.0f : 0.0f;
}

// ---------------- GEMM / pipeline kernels (fp64 accumulate) ----------------

// T[4096,64] = x[4096,512] @ Wg[512,64]
__global__ void k_xw(const float* __restrict__ x, const float* __restrict__ Wg,
                     double* __restrict__ T) {
    int col = threadIdx.x;                       // 64
    int row = blockIdx.x * 4 + threadIdx.y;      // 4 rows/block
    const float* xr = x + row * FF;
    double acc = 0.0;
    #pragma unroll 4
    for (int k = 0; k < FF; ++k)
        acc += (double)xr[k] * (double)Wg[k * HH + col];
    T[row * HH + col] = acc;
}

// h[4096,64] = relu(adj[4096,4096] @ T[4096,64] + bg)
__global__ void k_adjT(const float* __restrict__ adj, const double* __restrict__ T,
                       const float* __restrict__ bg, double* __restrict__ h) {
    __shared__ double Tl[128][HH];
    int tx = threadIdx.x, ty = threadIdx.y;
    int tid = ty * 64 + tx;
    int r0 = blockIdx.x * 16;
    const float* a0 = adj + (r0 + ty * 4) * NN;
    double acc[4] = {0.0, 0.0, 0.0, 0.0};
    for (int k0 = 0; k0 < NN; k0 += 128) {
        __syncthreads();
        for (int n = tid; n < 128 * HH; n += 256)
            ((double*)Tl)[n] = T[k0 * HH + n];
        __syncthreads();
        for (int kk = 0; kk < 128; ++kk) {
            double t = Tl[kk][tx];
            int k = k0 + kk;
            #pragma unroll
            for (int i = 0; i < 4; ++i)
                acc[i] += (double)a0[i * NN + k] * t;
        }
    }
    #pragma unroll
    for (int i = 0; i < 4; ++i) {
        double v = acc[i] + (double)bg[tx];
        h[(r0 + ty * 4 + i) * HH + tx] = v > 0.0 ? v : 0.0;
    }
}

// O[4096,64] = relu(A[4096,64] @ W[64,64] + b)
__global__ void k_small64(const double* __restrict__ A, const float* __restrict__ W,
                          const float* __restrict__ b, double* __restrict__ O) {
    __shared__ double Wl[HH][HH];
    int tx = threadIdx.x, ty = threadIdx.y;
    int tid = ty * 64 + tx;
    for (int n = tid; n < HH * HH; n += 256)
        ((double*)Wl)[n] = (double)W[n];
    __syncthreads();
    int row = blockIdx.x * 4 + ty;
    const double* Ar = A + row * HH;
    double acc = 0.0;
    #pragma unroll
    for (int k = 0; k < HH; ++k) acc += Ar[k] * Wl[k][tx];
    double v = acc + (double)b[tx];
    O[row * HH + tx] = v > 0.0 ? v : 0.0;
}

// Z[4096,512] = A[4096,64] @ W[64,512] + b
__global__ void k_projZ(const double* __restrict__ A, const float* __restrict__ W,
                        const float* __restrict__ b, double* __restrict__ Z) {
    int tx = threadIdx.x, ty = threadIdx.y;
    int row = blockIdx.y * 4 + ty;
    int col = blockIdx.x * 64 + tx;
    const double* Ar = A + row * HH;
    double acc = 0.0;
    #pragma unroll
    for (int k = 0; k < HH; ++k) acc += Ar[k] * (double)W[k * FF + col];
    Z[row * FF + col] = acc + (double)b[col];
}

// mask logits + feature-mask sampling fused: xnew = x * mask
__global__ void k_mask(const double* __restrict__ M1, const float* __restrict__ W,
                       const float* __restrict__ b, const float* __restrict__ x,
                       float* __restrict__ xnew, uint32_t k20, uint32_t k21,
                       double Lmin, double Lmax) {
    int tx = threadIdx.x, ty = threadIdx.y;
    int row = blockIdx.y * 4 + ty;
    int col = blockIdx.x * 64 + tx;
    const double* Ar = M1 + row * HH;
    double acc = 0.0;
    #pragma unroll
    for (int k = 0; k < HH; ++k) acc += Ar[k] * (double)W[k * FF + col];
    double ml = acc + (double)b[col];
    double l = ml < Lmin ? Lmin : (ml > Lmax ? Lmax : ml);
    uint32_t idx = (uint32_t)row * FF + (uint32_t)col;
    float u = jax_uniform(jax_bits32(k20, k21, idx));
    float m = hard_sample(l, u);
    xnew[idx] = (m != 0.0f) ? x[idx] : 0.0f;
}

// adj_logits = Z @ Z^T (symmetric; compute upper tile blocks, mirror-write), f32 out
#define ZS 129
__global__ void __launch_bounds__(256, 2)
k_zzt(const double* __restrict__ Z, float* __restrict__ out2) {
    __shared__ double La[32][ZS];
    __shared__ double Lb[32][ZS];
    int t = threadIdx.x;
    int tx = t & 15, ty = t >> 4;
    // decode triangular block id -> (bi, bj), bi <= bj, 32 tiles of 128
    int b = blockIdx.x, bi = 0;
    while (b >= 32 - bi) { b -= 32 - bi; ++bi; }
    int bj = bi + b;
    int rbase = bi * 128, cbase = bj * 128;
    double acc[8][8] = {};
    for (int k0 = 0; k0 < FF; k0 += 32) {
        __syncthreads();
        for (int n = t; n < 4096; n += 256) {
            int kk = n & 31, rr = n >> 5;
            La[kk][rr] = Z[(rbase + rr) * FF + k0 + kk];
            Lb[kk][rr] = Z[(cbase + rr) * FF + k0 + kk];
        }
        __syncthreads();
        for (int kk = 0; kk < 32; ++kk) {
            double a[8], bf[8];
            #pragma unroll
            for (int i = 0; i < 8; ++i) a[i] = La[kk][i * 16 + ty];
            #pragma unroll
            for (int j = 0; j < 8; ++j) bf[j] = Lb[kk][j * 16 + tx];
            #pragma unroll
            for (int i = 0; i < 8; ++i)
                #pragma unroll
                for (int j = 0; j < 8; ++j)
                    acc[i][j] += a[i] * bf[j];
        }
    }
    #pragma unroll
    for (int i = 0; i < 8; ++i) {
        #pragma unroll
        for (int j = 0; j < 8; ++j) {
            int r = rbase + i * 16 + ty;
            int c = cbase + j * 16 + tx;
            float v = (float)acc[i][j];
            out2[r * NN + c] = v;
            if (bi != bj) out2[c * NN + r] = v;
        }
    }
}

// edge sampling: a (0/1 with unit diagonal) -> out0, plus row sums
__global__ void k_sample_adj(const float* __restrict__ out2, float* __restrict__ out0,
                             float* __restrict__ rowsum, uint32_t k10, uint32_t k11,
                             double Lmin, double Lmax) {
    int i = blockIdx.y;
    int j = blockIdx.x * 256 + threadIdx.x;
    float aij;
    if (i == j) {
        aij = 1.0f;
    } else {
        int lo = i < j ? i : j;
        int hi = i < j ? j : i;
        uint32_t idx = (uint32_t)lo * NN + (uint32_t)hi;  // upper-triangle position
        double z = (double)out2[idx];
        double l = z < Lmin ? Lmin : (z > Lmax ? Lmax : z);
        float u = jax_uniform(jax_bits32(k10, k11, idx));
        aij = hard_sample(l, u);
    }
    out0[(size_t)i * NN + j] = aij;
    // reduce row contribution (exact: integer-valued floats)
    float v = aij;
    #pragma unroll
    for (int off = 32; off > 0; off >>= 1) v += __shfl_down(v, off, 64);
    __shared__ float wsum[4];
    int lane = threadIdx.x & 63, wid = threadIdx.x >> 6;
    if (lane == 0) wsum[wid] = v;
    __syncthreads();
    if (threadIdx.x == 0)
        atomicAdd(&rowsum[i], wsum[0] + wsum[1] + wsum[2] + wsum[3]);
}

__global__ void k_deg(const float* __restrict__ rowsum, double* __restrict__ dvec) {
    int i = blockIdx.x * 256 + threadIdx.x;
    dvec[i] = 1.0 / sqrt((double)rowsum[i]);
}

__global__ void k_scale(float* __restrict__ out0, const double* __restrict__ dvec) {
    int i = blockIdx.y;
    int j = blockIdx.x * 256 + threadIdx.x;
    size_t idx = (size_t)i * NN + j;
    float a = out0[idx];
    out0[idx] = (a != 0.0f) ? (float)(dvec[i] * dvec[j]) : 0.0f;
}

// ---------------- launch ----------------
extern "C" void kernel_launch(void* const* d_in, const int* in_sizes, int n_in,
                              void* d_out, int out_size, void* d_ws, size_t ws_size,
                              hipStream_t stream) {
    const float* adj = (const float*)d_in[0];
    const float* x   = (const float*)d_in[1];
    const float* Wg  = (const float*)d_in[2];
    const float* bg  = (const float*)d_in[3];
    const float* Wa1 = (const float*)d_in[4];
    const float* ba1 = (const float*)d_in[5];
    const float* Wa2 = (const float*)d_in[6];
    const float* ba2 = (const float*)d_in[7];
    const float* Wx1 = (const float*)d_in[8];
    const float* bx1 = (const float*)d_in[9];
    const float* Wx2 = (const float*)d_in[10];
    const float* bx2 = (const float*)d_in[11];

    float* out0 = (float*)d_out;                          // adj_norm [N,N]
    float* out1 = out0 + (size_t)NN * NN;                 // x_new [N,F]
    float* out2 = out1 + (size_t)NN * FF;                 // adj_logits [N,N]

    double* T    = (double*)d_ws;            // [4096,64]
    double* h    = T + NN * HH;              // [4096,64]
    double* A1   = h + NN * HH;              // [4096,64]
    double* M1   = A1 + NN * HH;             // [4096,64]
    double* Z    = M1 + NN * HH;             // [4096,512]
    double* dvec = Z + (size_t)NN * FF;      // [4096]
    float* rowsum = (float*)(dvec + NN);     // [4096]

    // JAX keys: base key(42) = (0,42); partitionable fold-like split
    uint32_t k1a, k1b, k2a, k2b;
    threefry2x32(0u, 42u, 0u, 0u, k1a, k1b);  // k1 (adjacency noise)
    threefry2x32(0u, 42u, 0u, 1u, k2a, k2b);  // k2 (feature-mask noise)

    const double Lmax = std::log(1.0 - 1e-6) - std::log1p(-(1.0 - 1e-6));
    const double Lmin = std::log(1e-6) - std::log1p(-1e-6);

    k_xw<<<NN / 4, dim3(64, 4), 0, stream>>>(x, Wg, T);
    k_adjT<<<NN / 16, dim3(64, 4), 0, stream>>>(adj, T, bg, h);
    k_small64<<<NN / 4, dim3(64, 4), 0, stream>>>(h, Wa1, ba1, A1);
    k_projZ<<<dim3(FF / 64, NN / 4), dim3(64, 4), 0, stream>>>(A1, Wa2, ba2, Z);
    k_zzt<<<528, 256, 0, stream>>>(Z, out2);

    hipMemsetAsync(rowsum, 0, NN * sizeof(float), stream);
    k_sample_adj<<<dim3(NN / 256, NN), 256, 0, stream>>>(out2, out0, rowsum,
                                                         k1a, k1b, Lmin, Lmax);
    k_deg<<<NN / 256, 256, 0, stream>>>(rowsum, dvec);
    k_scale<<<dim3(NN / 256, NN), 256, 0, stream>>>(out0, dvec);

    k_small64<<<NN / 4, dim3(64, 4), 0, stream>>>(h, Wx1, bx1, M1);
    k_mask<<<dim3(FF / 64, NN / 4), dim3(64, 4), 0, stream>>>(M1, Wx2, bx2, x, out1,
                                                              k2a, k2b, Lmin, Lmax);
}

// Round 2
// 942.189 us; speedup vs baseline: 1.3924x; 1.3924x over previous
//
#include <hip/hip_runtime.h>
#include <hip/hip_bf16.h>
#include <cstdint>
#include <cmath>

#define NN 4096
#define FF 512
#define HH 64
#define KSPLIT 8

// ---------------- threefry2x32 (JAX-compatible, 20 rounds) ----------------
__host__ __device__ __forceinline__ uint32_t rotl32(uint32_t x, int r) {
    return (x << r) | (x >> (32 - r));
}

__host__ __device__ __forceinline__ void threefry2x32(uint32_t ks0, uint32_t ks1,
                                                      uint32_t x0, uint32_t x1,
                                                      uint32_t& o0, uint32_t& o1) {
    uint32_t ks2 = ks0 ^ ks1 ^ 0x1BD11BDAu;
    x0 += ks0; x1 += ks1;
    x0 += x1; x1 = rotl32(x1, 13); x1 ^= x0;
    x0 += x1; x1 = rotl32(x1, 15); x1 ^= x0;
    x0 += x1; x1 = rotl32(x1, 26); x1 ^= x0;
    x0 += x1; x1 = rotl32(x1,  6); x1 ^= x0;
    x0 += ks1; x1 += ks2 + 1u;
    x0 += x1; x1 = rotl32(x1, 17); x1 ^= x0;
    x0 += x1; x1 = rotl32(x1, 29); x1 ^= x0;
    x0 += x1; x1 = rotl32(x1, 16); x1 ^= x0;
    x0 += x1; x1 = rotl32(x1, 24); x1 ^= x0;
    x0 += ks2; x1 += ks0 + 2u;
    x0 += x1; x1 = rotl32(x1, 13); x1 ^= x0;
    x0 += x1; x1 = rotl32(x1, 15); x1 ^= x0;
    x0 += x1; x1 = rotl32(x1, 26); x1 ^= x0;
    x0 += x1; x1 = rotl32(x1,  6); x1 ^= x0;
    x0 += ks0; x1 += ks1 + 3u;
    x0 += x1; x1 = rotl32(x1, 17); x1 ^= x0;
    x0 += x1; x1 = rotl32(x1, 29); x1 ^= x0;
    x0 += x1; x1 = rotl32(x1, 16); x1 ^= x0;
    x0 += x1; x1 = rotl32(x1, 24); x1 ^= x0;
    x0 += ks1; x1 += ks2 + 4u;
    x0 += x1; x1 = rotl32(x1, 13); x1 ^= x0;
    x0 += x1; x1 = rotl32(x1, 15); x1 ^= x0;
    x0 += x1; x1 = rotl32(x1, 26); x1 ^= x0;
    x0 += x1; x1 = rotl32(x1,  6); x1 ^= x0;
    x0 += ks2; x1 += ks0 + 5u;
    o0 = x0; o1 = x1;
}

__device__ __forceinline__ uint32_t jax_bits32(uint32_t k0, uint32_t k1, uint32_t j) {
    uint32_t b0, b1;
    threefry2x32(k0, k1, 0u, j, b0, b1);
    return b0 ^ b1;
}

__device__ __forceinline__ float jax_uniform(uint32_t bits) {
    const float minv = 1e-6f;
    const float maxv = (float)(1.0 - 1e-6);
    const float span = maxv - minv;
    float f = __uint_as_float((bits >> 9) | 0x3f800000u) - 1.0f;
    float u = __fadd_rn(__fmul_rn(f, span), minv);
    return fmaxf(minv, u);
}

// hard Bernoulli-ST forward: 1[ l + logit(u) > 0 ]  <=>  u > 1/(1+e^l)
__device__ __forceinline__ float hard_sample(double l, float u32) {
    double thr = 1.0 / (1.0 + exp(l));
    return ((double)u32 > thr) ? 1.0f : 0.0f;
}

// ---------------- pipeline kernels (fp64 accumulate) ----------------

// T[4096,64] = x[4096,512] @ Wg[512,64]
__global__ void k_xw(const float* __restrict__ x, const float* __restrict__ Wg,
                     double* __restrict__ T) {
    int col = threadIdx.x;
    int row = blockIdx.x * 4 + threadIdx.y;
    const float* xr = x + row * FF;
    double acc = 0.0;
    #pragma unroll 4
    for (int k = 0; k < FF; ++k)
        acc += (double)xr[k] * (double)Wg[k * HH + col];
    T[row * HH + col] = acc;
}

// adjT v2: LDS-tiled, K-split partials. partial[s][4096][64]
__global__ void __launch_bounds__(256)
k_adjT2(const float* __restrict__ adj, const double* __restrict__ T,
        double* __restrict__ partial) {
    __shared__ float As[64][68];    // padded: conflict-free reads, 16B-aligned rows
    __shared__ double Ts[64][64];
    int t = threadIdx.x;
    int tx = t & 15, ty = t >> 4;   // tx: col quad, ty: row quad
    int r0 = blockIdx.x * 64;
    int kb = blockIdx.y * (NN / KSPLIT);
    double acc[4][4] = {};
    for (int k0 = 0; k0 < NN / KSPLIT; k0 += 64) {
        __syncthreads();
        // A tile 64x64 fp32: 1024 float4 loads, coalesced
        for (int n = t; n < 1024; n += 256) {
            int rr = n >> 4, kq = n & 15;
            float4 v = *(const float4*)&adj[(size_t)(r0 + rr) * NN + kb + k0 + kq * 4];
            *(float4*)&As[rr][kq * 4] = v;
        }
        // T tile 64x64 fp64: 2048 double2 loads
        for (int n = t; n < 2048; n += 256) {
            int rr = n >> 5, kq = n & 31;
            double2 v = *(const double2*)&T[(size_t)(kb + k0 + rr) * HH + kq * 2];
            *(double2*)&Ts[rr][kq * 2] = v;
        }
        __syncthreads();
        for (int kk = 0; kk < 64; ++kk) {
            double a[4], b[4];
            #pragma unroll
            for (int i = 0; i < 4; ++i) a[i] = (double)As[ty * 4 + i][kk];
            double2 b01 = *(double2*)&Ts[kk][tx * 4];
            double2 b23 = *(double2*)&Ts[kk][tx * 4 + 2];
            b[0] = b01.x; b[1] = b01.y; b[2] = b23.x; b[3] = b23.y;
            #pragma unroll
            for (int i = 0; i < 4; ++i)
                #pragma unroll
                for (int j = 0; j < 4; ++j)
                    acc[i][j] += a[i] * b[j];
        }
    }
    double* P = partial + (size_t)blockIdx.y * NN * HH;
    #pragma unroll
    for (int i = 0; i < 4; ++i) {
        int row = r0 + ty * 4 + i;
        #pragma unroll
        for (int j = 0; j < 4; j += 2) {
            double2 v; v.x = acc[i][j]; v.y = acc[i][j + 1];
            *(double2*)&P[(size_t)row * HH + tx * 4 + j] = v;
        }
    }
}

// h = relu(sum_s partial[s] + bg), deterministic order
__global__ void k_hred(const double* __restrict__ partial, const float* __restrict__ bg,
                       double* __restrict__ h) {
    int idx = blockIdx.x * 256 + threadIdx.x;
    double s = 0.0;
    #pragma unroll
    for (int p = 0; p < KSPLIT; ++p) s += partial[(size_t)p * NN * HH + idx];
    double v = s + (double)bg[idx & (HH - 1)];
    h[idx] = v > 0.0 ? v : 0.0;
}

// O[4096,64] = relu(A[4096,64] @ W[64,64] + b)
__global__ void k_small64(const double* __restrict__ A, const float* __restrict__ W,
                          const float* __restrict__ b, double* __restrict__ O) {
    __shared__ double Wl[HH][HH];
    int tx = threadIdx.x, ty = threadIdx.y;
    int tid = ty * 64 + tx;
    for (int n = tid; n < HH * HH; n += 256)
        ((double*)Wl)[n] = (double)W[n];
    __syncthreads();
    int row = blockIdx.x * 4 + ty;
    const double* Ar = A + row * HH;
    double acc = 0.0;
    #pragma unroll
    for (int k = 0; k < HH; ++k) acc += Ar[k] * Wl[k][tx];
    double v = acc + (double)b[tx];
    O[row * HH + tx] = v > 0.0 ? v : 0.0;
}

// Z[4096,512] = A[4096,64] @ W[64,512] + b
__global__ void k_projZ(const double* __restrict__ A, const float* __restrict__ W,
                        const float* __restrict__ b, double* __restrict__ Z) {
    int tx = threadIdx.x, ty = threadIdx.y;
    int row = blockIdx.y * 4 + ty;
    int col = blockIdx.x * 64 + tx;
    const double* Ar = A + row * HH;
    double acc = 0.0;
    #pragma unroll
    for (int k = 0; k < HH; ++k) acc += Ar[k] * (double)W[k * FF + col];
    Z[row * FF + col] = acc + (double)b[col];
}

// mask logits + feature-mask sampling fused: xnew = x * mask
__global__ void k_mask(const double* __restrict__ M1, const float* __restrict__ W,
                       const float* __restrict__ b, const float* __restrict__ x,
                       float* __restrict__ xnew, uint32_t k20, uint32_t k21,
                       double Lmin, double Lmax) {
    int tx = threadIdx.x, ty = threadIdx.y;
    int row = blockIdx.y * 4 + ty;
    int col = blockIdx.x * 64 + tx;
    const double* Ar = M1 + row * HH;
    double acc = 0.0;
    #pragma unroll
    for (int k = 0; k < HH; ++k) acc += Ar[k] * (double)W[k * FF + col];
    double ml = acc + (double)b[col];
    double l = ml < Lmin ? Lmin : (ml > Lmax ? Lmax : ml);
    uint32_t idx = (uint32_t)row * FF + (uint32_t)col;
    float u = jax_uniform(jax_bits32(k20, k21, idx));
    float m = hard_sample(l, u);
    xnew[idx] = (m != 0.0f) ? x[idx] : 0.0f;
}

// adj_logits = Z @ Z^T (triangular blocks, mirror-write) + fused edge sampling
// + rowsum accumulation (0/1 integer floats: order-independent, exact)
#define ZS 129
__global__ void __launch_bounds__(256, 2)
k_zzt(const double* __restrict__ Z, float* __restrict__ out2, float* __restrict__ out0,
      float* __restrict__ rowsum, uint32_t k10, uint32_t k11,
      double Lmin, double Lmax) {
    __shared__ double La[32][ZS];
    __shared__ double Lb[32][ZS];
    __shared__ float rs[128], cs[128];
    int t = threadIdx.x;
    int tx = t & 15, ty = t >> 4;
    if (t < 128) { rs[t] = 0.0f; cs[t] = 0.0f; }
    // decode triangular block id -> (bi, bj), bi <= bj, 32 tiles of 128
    int b = blockIdx.x, bi = 0;
    while (b >= 32 - bi) { b -= 32 - bi; ++bi; }
    int bj = bi + b;
    int rbase = bi * 128, cbase = bj * 128;
    double acc[8][8] = {};
    for (int k0 = 0; k0 < FF; k0 += 32) {
        __syncthreads();
        for (int n = t; n < 4096; n += 256) {
            int kk = n & 31, rr = n >> 5;
            La[kk][rr] = Z[(rbase + rr) * FF + k0 + kk];
            Lb[kk][rr] = Z[(cbase + rr) * FF + k0 + kk];
        }
        __syncthreads();
        for (int kk = 0; kk < 32; ++kk) {
            double a[8], bf[8];
            #pragma unroll
            for (int i = 0; i < 8; ++i) a[i] = La[kk][i * 16 + ty];
            #pragma unroll
            for (int j = 0; j < 8; ++j) bf[j] = Lb[kk][j * 16 + tx];
            #pragma unroll
            for (int i = 0; i < 8; ++i)
                #pragma unroll
                for (int j = 0; j < 8; ++j)
                    acc[i][j] += a[i] * bf[j];
        }
    }
    float rowpart[8] = {}, colpart[8] = {};
    #pragma unroll
    for (int i = 0; i < 8; ++i) {
        #pragma unroll
        for (int j = 0; j < 8; ++j) {
            int r = rbase + i * 16 + ty;
            int c = cbase + j * 16 + tx;
            float v = (float)acc[i][j];
            out2[(size_t)r * NN + c] = v;
            if (bi != bj) out2[(size_t)c * NN + r] = v;
            if (r < c) {
                double z = acc[i][j];
                double l = z < Lmin ? Lmin : (z > Lmax ? Lmax : z);
                uint32_t idx = (uint32_t)r * NN + (uint32_t)c;
                float u = jax_uniform(jax_bits32(k10, k11, idx));
                float aij = hard_sample(l, u);
                out0[(size_t)r * NN + c] = aij;
                out0[(size_t)c * NN + r] = aij;
                rowpart[i] += aij;
                colpart[j] += aij;
            } else if (r == c) {
                out0[(size_t)r * NN + c] = 1.0f;
                rowpart[i] += 1.0f;
            }
        }
    }
    #pragma unroll
    for (int i = 0; i < 8; ++i) atomicAdd(&rs[i * 16 + ty], rowpart[i]);
    #pragma unroll
    for (int j = 0; j < 8; ++j) atomicAdd(&cs[j * 16 + tx], colpart[j]);
    __syncthreads();
    if (t < 128) {
        atomicAdd(&rowsum[rbase + t], rs[t]);
        atomicAdd(&rowsum[cbase + t], cs[t]);
    }
}

__global__ void k_deg(const float* __restrict__ rowsum, double* __restrict__ dvec) {
    int i = blockIdx.x * 256 + threadIdx.x;
    dvec[i] = 1.0 / sqrt((double)rowsum[i]);
}

__global__ void k_scale(float* __restrict__ out0, const double* __restrict__ dvec) {
    int i = blockIdx.y;
    int j = blockIdx.x * 256 + threadIdx.x;
    size_t idx = (size_t)i * NN + j;
    float a = out0[idx];
    out0[idx] = (a != 0.0f) ? (float)(dvec[i] * dvec[j]) : 0.0f;
}

// ---------------- launch ----------------
extern "C" void kernel_launch(void* const* d_in, const int* in_sizes, int n_in,
                              void* d_out, int out_size, void* d_ws, size_t ws_size,
                              hipStream_t stream) {
    const float* adj = (const float*)d_in[0];
    const float* x   = (const float*)d_in[1];
    const float* Wg  = (const float*)d_in[2];
    const float* bg  = (const float*)d_in[3];
    const float* Wa1 = (const float*)d_in[4];
    const float* ba1 = (const float*)d_in[5];
    const float* Wa2 = (const float*)d_in[6];
    const float* ba2 = (const float*)d_in[7];
    const float* Wx1 = (const float*)d_in[8];
    const float* bx1 = (const float*)d_in[9];
    const float* Wx2 = (const float*)d_in[10];
    const float* bx2 = (const float*)d_in[11];

    float* out0 = (float*)d_out;                          // adj_norm [N,N]
    float* out1 = out0 + (size_t)NN * NN;                 // x_new [N,F]
    float* out2 = out1 + (size_t)NN * FF;                 // adj_logits [N,N]

    double* T    = (double*)d_ws;            // [4096,64]
    double* h    = T + NN * HH;              // [4096,64]
    double* A1   = h + NN * HH;              // [4096,64]
    double* M1   = A1 + NN * HH;             // [4096,64]
    double* Z    = M1 + NN * HH;             // [4096,512]  (16.77 MB)
    double* dvec = Z + (size_t)NN * FF;      // [4096]
    float* rowsum = (float*)(dvec + NN);     // [4096]
    // partial overlays Z: same byte size (KSPLIT*N*H*8 == N*F*8), consumed
    // by k_hred before k_projZ writes Z.
    double* partial = Z;

    uint32_t k1a, k1b, k2a, k2b;
    threefry2x32(0u, 42u, 0u, 0u, k1a, k1b);  // adjacency noise key
    threefry2x32(0u, 42u, 0u, 1u, k2a, k2b);  // feature-mask noise key

    const double Lmax = std::log(1.0 - 1e-6) - std::log1p(-(1.0 - 1e-6));
    const double Lmin = std::log(1e-6) - std::log1p(-1e-6);

    k_xw<<<NN / 4, dim3(64, 4), 0, stream>>>(x, Wg, T);
    k_adjT2<<<dim3(64, KSPLIT), 256, 0, stream>>>(adj, T, partial);
    k_hred<<<NN * HH / 256, 256, 0, stream>>>(partial, bg, h);
    k_small64<<<NN / 4, dim3(64, 4), 0, stream>>>(h, Wa1, ba1, A1);
    k_projZ<<<dim3(FF / 64, NN / 4), dim3(64, 4), 0, stream>>>(A1, Wa2, ba2, Z);

    hipMemsetAsync(rowsum, 0, NN * sizeof(float), stream);
    k_zzt<<<528, 256, 0, stream>>>(Z, out2, out0, rowsum, k1a, k1b, Lmin, Lmax);
    k_deg<<<NN / 256, 256, 0, stream>>>(rowsum, dvec);
    k_scale<<<dim3(NN / 256, NN), 256, 0, stream>>>(out0, dvec);

    k_small64<<<NN / 4, dim3(64, 4), 0, stream>>>(h, Wx1, bx1, M1);
    k_mask<<<dim3(FF / 64, NN / 4), dim3(64, 4), 0, stream>>>(M1, Wx2, bx2, x, out1,
                                                              k2a, k2b, Lmin, Lmax);
}

// Round 4
// 517.838 us; speedup vs baseline: 2.5334x; 1.8195x over previous
//
#include <hip/hip_runtime.h>
#include <cstdint>
#include <cmath>

#define NN 4096
#define FF 512
#define HH 64
#define KSPLIT 8

typedef unsigned short ushort_t;
typedef short bf16x8 __attribute__((ext_vector_type(8)));
typedef float f32x4 __attribute__((ext_vector_type(4)));

// ---------------- threefry2x32 (JAX-compatible, 20 rounds) ----------------
__host__ __device__ __forceinline__ uint32_t rotl32(uint32_t x, int r) {
    return (x << r) | (x >> (32 - r));
}

__host__ __device__ __forceinline__ void threefry2x32(uint32_t ks0, uint32_t ks1,
                                                      uint32_t x0, uint32_t x1,
                                                      uint32_t& o0, uint32_t& o1) {
    uint32_t ks2 = ks0 ^ ks1 ^ 0x1BD11BDAu;
    x0 += ks0; x1 += ks1;
    x0 += x1; x1 = rotl32(x1, 13); x1 ^= x0;
    x0 += x1; x1 = rotl32(x1, 15); x1 ^= x0;
    x0 += x1; x1 = rotl32(x1, 26); x1 ^= x0;
    x0 += x1; x1 = rotl32(x1,  6); x1 ^= x0;
    x0 += ks1; x1 += ks2 + 1u;
    x0 += x1; x1 = rotl32(x1, 17); x1 ^= x0;
    x0 += x1; x1 = rotl32(x1, 29); x1 ^= x0;
    x0 += x1; x1 = rotl32(x1, 16); x1 ^= x0;
    x0 += x1; x1 = rotl32(x1, 24); x1 ^= x0;
    x0 += ks2; x1 += ks0 + 2u;
    x0 += x1; x1 = rotl32(x1, 13); x1 ^= x0;
    x0 += x1; x1 = rotl32(x1, 15); x1 ^= x0;
    x0 += x1; x1 = rotl32(x1, 26); x1 ^= x0;
    x0 += x1; x1 = rotl32(x1,  6); x1 ^= x0;
    x0 += ks0; x1 += ks1 + 3u;
    x0 += x1; x1 = rotl32(x1, 17); x1 ^= x0;
    x0 += x1; x1 = rotl32(x1, 29); x1 ^= x0;
    x0 += x1; x1 = rotl32(x1, 16); x1 ^= x0;
    x0 += x1; x1 = rotl32(x1, 24); x1 ^= x0;
    x0 += ks1; x1 += ks2 + 4u;
    x0 += x1; x1 = rotl32(x1, 13); x1 ^= x0;
    x0 += x1; x1 = rotl32(x1, 15); x1 ^= x0;
    x0 += x1; x1 = rotl32(x1, 26); x1 ^= x0;
    x0 += x1; x1 = rotl32(x1,  6); x1 ^= x0;
    x0 += ks2; x1 += ks0 + 5u;
    o0 = x0; o1 = x1;
}

__device__ __forceinline__ uint32_t jax_bits32(uint32_t k0, uint32_t k1, uint32_t j) {
    uint32_t b0, b1;
    threefry2x32(k0, k1, 0u, j, b0, b1);
    return b0 ^ b1;
}

__device__ __forceinline__ float jax_uniform(uint32_t bits) {
    const float minv = 1e-6f;
    const float maxv = (float)(1.0 - 1e-6);
    const float span = maxv - minv;
    float f = __uint_as_float((bits >> 9) | 0x3f800000u) - 1.0f;
    float u = __fadd_rn(__fmul_rn(f, span), minv);
    return fmaxf(minv, u);
}

// hard Bernoulli-ST forward: 1[ l + logit(u) > 0 ]  <=>  u > 1/(1+e^l)
__device__ __forceinline__ float hard_sample_f(float l, float u) {
    float thr = 1.0f / (1.0f + expf(l));
    return (u > thr) ? 1.0f : 0.0f;
}

__device__ __forceinline__ ushort_t f32_to_bf16_rne(float f) {
    uint32_t x = __float_as_uint(f);
    uint32_t r = (x + 0x7fffu + ((x >> 16) & 1u)) >> 16;
    return (ushort_t)r;
}

// ---------------- pipeline kernels (all fp32) ----------------

// T[4096,64] = x[4096,512] @ Wg[512,64]
__global__ void k_xw(const float* __restrict__ x, const float* __restrict__ Wg,
                     float* __restrict__ T) {
    int col = threadIdx.x;
    int row = blockIdx.x * 4 + threadIdx.y;
    const float* xr = x + row * FF;
    float acc = 0.0f;
    #pragma unroll 4
    for (int k = 0; k < FF; ++k)
        acc += xr[k] * Wg[k * HH + col];
    T[row * HH + col] = acc;
}

// adjT: LDS-tiled f32, K-split partials. partial[s][4096][64]
__global__ void __launch_bounds__(256)
k_adjT2(const float* __restrict__ adj, const float* __restrict__ T,
        float* __restrict__ partial) {
    __shared__ __align__(16) float As[64][68];
    __shared__ __align__(16) float Ts[64][64];
    int t = threadIdx.x;
    int tx = t & 15, ty = t >> 4;
    int r0 = blockIdx.x * 64;
    int kb = blockIdx.y * (NN / KSPLIT);
    float acc[4][4] = {};
    for (int k0 = 0; k0 < NN / KSPLIT; k0 += 64) {
        __syncthreads();
        for (int n = t; n < 1024; n += 256) {
            int rr = n >> 4, kq = n & 15;
            float4 v = *(const float4*)&adj[(size_t)(r0 + rr) * NN + kb + k0 + kq * 4];
            *(float4*)&As[rr][kq * 4] = v;
        }
        for (int n = t; n < 1024; n += 256) {
            int rr = n >> 4, kq = n & 15;
            float4 v = *(const float4*)&T[(size_t)(kb + k0 + rr) * HH + kq * 4];
            *(float4*)&Ts[rr][kq * 4] = v;
        }
        __syncthreads();
        for (int kk = 0; kk < 64; ++kk) {
            float a[4];
            #pragma unroll
            for (int i = 0; i < 4; ++i) a[i] = As[ty * 4 + i][kk];
            float4 bv = *(float4*)&Ts[kk][tx * 4];
            float b[4] = {bv.x, bv.y, bv.z, bv.w};
            #pragma unroll
            for (int i = 0; i < 4; ++i)
                #pragma unroll
                for (int j = 0; j < 4; ++j)
                    acc[i][j] += a[i] * b[j];
        }
    }
    float* P = partial + (size_t)blockIdx.y * NN * HH;
    #pragma unroll
    for (int i = 0; i < 4; ++i) {
        int row = r0 + ty * 4 + i;
        float4 v = {acc[i][0], acc[i][1], acc[i][2], acc[i][3]};
        *(float4*)&P[(size_t)row * HH + tx * 4] = v;
    }
}

// h = relu(sum_s partial[s] + bg)
__global__ void k_hred(const float* __restrict__ partial, const float* __restrict__ bg,
                       float* __restrict__ h) {
    int idx = blockIdx.x * 256 + threadIdx.x;
    float s = 0.0f;
    #pragma unroll
    for (int p = 0; p < KSPLIT; ++p) s += partial[(size_t)p * NN * HH + idx];
    float v = s + bg[idx & (HH - 1)];
    h[idx] = v > 0.0f ? v : 0.0f;
}

// O[4096,64] = relu(A[4096,64] @ W[64,64] + b)
__global__ void k_small64(const float* __restrict__ A, const float* __restrict__ W,
                          const float* __restrict__ b, float* __restrict__ O) {
    __shared__ float Wl[HH][HH];
    int tx = threadIdx.x, ty = threadIdx.y;
    int tid = ty * 64 + tx;
    for (int n = tid; n < HH * HH; n += 256)
        ((float*)Wl)[n] = W[n];
    __syncthreads();
    int row = blockIdx.x * 4 + ty;
    const float* Ar = A + row * HH;
    float acc = 0.0f;
    #pragma unroll
    for (int k = 0; k < HH; ++k) acc += Ar[k] * Wl[k][tx];
    float v = acc + b[tx];
    O[row * HH + tx] = v > 0.0f ? v : 0.0f;
}

// Zb[4096,512] (bf16) = A[4096,64] @ W[64,512] + b
__global__ void k_projZ(const float* __restrict__ A, const float* __restrict__ W,
                        const float* __restrict__ b, ushort_t* __restrict__ Zb) {
    int tx = threadIdx.x, ty = threadIdx.y;
    int row = blockIdx.y * 4 + ty;
    int col = blockIdx.x * 64 + tx;
    const float* Ar = A + row * HH;
    float acc = 0.0f;
    #pragma unroll
    for (int k = 0; k < HH; ++k) acc += Ar[k] * W[k * FF + col];
    Zb[(size_t)row * FF + col] = f32_to_bf16_rne(acc + b[col]);
}

// mask logits + feature-mask sampling fused: xnew = x * mask
__global__ void k_mask(const float* __restrict__ M1, const float* __restrict__ W,
                       const float* __restrict__ b, const float* __restrict__ x,
                       float* __restrict__ xnew, uint32_t k20, uint32_t k21,
                       float Lmin, float Lmax) {
    int tx = threadIdx.x, ty = threadIdx.y;
    int row = blockIdx.y * 4 + ty;
    int col = blockIdx.x * 64 + tx;
    const float* Ar = M1 + row * HH;
    float acc = 0.0f;
    #pragma unroll
    for (int k = 0; k < HH; ++k) acc += Ar[k] * W[k * FF + col];
    float ml = acc + b[col];
    float l = ml < Lmin ? Lmin : (ml > Lmax ? Lmax : ml);
    uint32_t idx = (uint32_t)row * FF + (uint32_t)col;
    float u = jax_uniform(jax_bits32(k20, k21, idx));
    float m = hard_sample_f(l, u);
    xnew[idx] = (m != 0.0f) ? x[idx] : 0.0f;
}

// adj_logits = Zb @ Zb^T via bf16 MFMA (triangular blocks, mirror-write)
// + fused edge sampling + rowsum accumulation.
// mfma_f32_16x16x32_bf16 fragments (gfx950 HW-verified):
//   A: m=lane&15, k=(lane>>4)*8+j  (8 contiguous bf16 along k)
//   B: n=lane&15, k=(lane>>4)*8+j
//   D: col=lane&15, row=(lane>>4)*4+reg
__global__ void __launch_bounds__(256)
k_zzt(const ushort_t* __restrict__ Zb, float* __restrict__ out2,
      float* __restrict__ out0, float* __restrict__ rowsum,
      uint32_t k10, uint32_t k11, float Lmin, float Lmax) {
    __shared__ __align__(16) ushort_t At[128][72];   // +8 pad: 144B stride, 2-way banks (free)
    __shared__ __align__(16) ushort_t Bt[128][72];
    __shared__ float rs[128], cs[128];
    int t = threadIdx.x;
    int lane = t & 63, w = t >> 6;
    int lr = lane & 15, lk = lane >> 4;
    if (t < 128) { rs[t] = 0.0f; cs[t] = 0.0f; }
    int b = blockIdx.x, bi = 0;
    while (b >= 32 - bi) { b -= 32 - bi; ++bi; }
    int bj = bi + b;
    int rbase = bi * 128, cbase = bj * 128;
    f32x4 acc[2][8] = {};
    for (int k0 = 0; k0 < FF; k0 += 64) {
        __syncthreads();
        for (int n = t; n < 1024; n += 256) {
            int rr = n >> 3, ck = n & 7;
            *(uint4*)&At[rr][ck * 8] = *(const uint4*)&Zb[(size_t)(rbase + rr) * FF + k0 + ck * 8];
            *(uint4*)&Bt[rr][ck * 8] = *(const uint4*)&Zb[(size_t)(cbase + rr) * FF + k0 + ck * 8];
        }
        __syncthreads();
        #pragma unroll
        for (int ks = 0; ks < 2; ++ks) {
            bf16x8 a0 = *(const bf16x8*)&At[w * 32 + lr][ks * 32 + lk * 8];
            bf16x8 a1 = *(const bf16x8*)&At[w * 32 + 16 + lr][ks * 32 + lk * 8];
            #pragma unroll
            for (int j = 0; j < 8; ++j) {
                bf16x8 bb = *(const bf16x8*)&Bt[j * 16 + lr][ks * 32 + lk * 8];
                acc[0][j] = __builtin_amdgcn_mfma_f32_16x16x32_bf16(a0, bb, acc[0][j], 0, 0, 0);
                acc[1][j] = __builtin_amdgcn_mfma_f32_16x16x32_bf16(a1, bb, acc[1][j], 0, 0, 0);
            }
        }
    }
    float rowpart[2][4] = {};
    float colpart[8] = {};
    #pragma unroll
    for (int it = 0; it < 2; ++it) {
        #pragma unroll
        for (int j = 0; j < 8; ++j) {
            #pragma unroll
            for (int reg = 0; reg < 4; ++reg) {
                int r = rbase + w * 32 + it * 16 + lk * 4 + reg;
                int c = cbase + j * 16 + lr;
                float z = acc[it][j][reg];
                out2[(size_t)r * NN + c] = z;
                if (bi != bj) out2[(size_t)c * NN + r] = z;
                if (r < c) {
                    float l = z < Lmin ? Lmin : (z > Lmax ? Lmax : z);
                    uint32_t idx = (uint32_t)r * NN + (uint32_t)c;
                    float u = jax_uniform(jax_bits32(k10, k11, idx));
                    float aij = hard_sample_f(l, u);
                    out0[(size_t)r * NN + c] = aij;
                    out0[(size_t)c * NN + r] = aij;
                    rowpart[it][reg] += aij;
                    colpart[j] += aij;
                } else if (r == c) {
                    out0[(size_t)r * NN + c] = 1.0f;
                    rowpart[it][reg] += 1.0f;
                }
            }
        }
    }
    #pragma unroll
    for (int it = 0; it < 2; ++it)
        #pragma unroll
        for (int reg = 0; reg < 4; ++reg)
            atomicAdd(&rs[w * 32 + it * 16 + lk * 4 + reg], rowpart[it][reg]);
    #pragma unroll
    for (int j = 0; j < 8; ++j)
        atomicAdd(&cs[j * 16 + lr], colpart[j]);
    __syncthreads();
    if (t < 128) {
        atomicAdd(&rowsum[rbase + t], rs[t]);
        atomicAdd(&rowsum[cbase + t], cs[t]);
    }
}

__global__ void k_deg(const float* __restrict__ rowsum, float* __restrict__ dvec) {
    int i = blockIdx.x * 256 + threadIdx.x;
    dvec[i] = 1.0f / sqrtf(rowsum[i]);
}

__global__ void k_scale(float* __restrict__ out0, const float* __restrict__ dvec) {
    int i = blockIdx.y;
    int j = blockIdx.x * 256 + threadIdx.x;
    size_t idx = (size_t)i * NN + j;
    float a = out0[idx];
    out0[idx] = (a != 0.0f) ? dvec[i] * dvec[j] : 0.0f;
}

// ---------------- launch ----------------
extern "C" void kernel_launch(void* const* d_in, const int* in_sizes, int n_in,
                              void* d_out, int out_size, void* d_ws, size_t ws_size,
                              hipStream_t stream) {
    const float* adj = (const float*)d_in[0];
    const float* x   = (const float*)d_in[1];
    const float* Wg  = (const float*)d_in[2];
    const float* bg  = (const float*)d_in[3];
    const float* Wa1 = (const float*)d_in[4];
    const float* ba1 = (const float*)d_in[5];
    const float* Wa2 = (const float*)d_in[6];
    const float* ba2 = (const float*)d_in[7];
    const float* Wx1 = (const float*)d_in[8];
    const float* bx1 = (const float*)d_in[9];
    const float* Wx2 = (const float*)d_in[10];
    const float* bx2 = (const float*)d_in[11];

    float* out0 = (float*)d_out;                          // adj_norm [N,N]
    float* out1 = out0 + (size_t)NN * NN;                 // x_new [N,F]
    float* out2 = out1 + (size_t)NN * FF;                 // adj_logits [N,N]

    float* T       = (float*)d_ws;                 // [4096,64]   1 MB
    float* h       = T + NN * HH;                  // [4096,64]   1 MB
    float* A1      = h + NN * HH;                  // [4096,64]   1 MB
    float* M1      = A1 + NN * HH;                 // [4096,64]   1 MB
    ushort_t* Zb   = (ushort_t*)(M1 + NN * HH);    // [4096,512] bf16, 4 MB
    float* partial = (float*)(Zb + (size_t)NN * FF); // [8][4096,64] 8 MB
    float* dvec    = partial + (size_t)KSPLIT * NN * HH;
    float* rowsum  = dvec + NN;

    uint32_t k1a, k1b, k2a, k2b;
    threefry2x32(0u, 42u, 0u, 0u, k1a, k1b);  // adjacency noise key
    threefry2x32(0u, 42u, 0u, 1u, k2a, k2b);  // feature-mask noise key

    const float Lmax = (float)(std::log(1.0 - 1e-6) - std::log1p(-(1.0 - 1e-6)));
    const float Lmin = (float)(std::log(1e-6) - std::log1p(-1e-6));

    k_xw<<<NN / 4, dim3(64, 4), 0, stream>>>(x, Wg, T);
    k_adjT2<<<dim3(64, KSPLIT), 256, 0, stream>>>(adj, T, partial);
    k_hred<<<NN * HH / 256, 256, 0, stream>>>(partial, bg, h);
    k_small64<<<NN / 4, dim3(64, 4), 0, stream>>>(h, Wa1, ba1, A1);
    k_projZ<<<dim3(FF / 64, NN / 4), dim3(64, 4), 0, stream>>>(A1, Wa2, ba2, Zb);

    hipMemsetAsync(rowsum, 0, NN * sizeof(float), stream);
    k_zzt<<<528, 256, 0, stream>>>(Zb, out2, out0, rowsum, k1a, k1b, Lmin, Lmax);
    k_deg<<<NN / 256, 256, 0, stream>>>(rowsum, dvec);
    k_scale<<<dim3(NN / 256, NN), 256, 0, stream>>>(out0, dvec);

    k_small64<<<NN / 4, dim3(64, 4), 0, stream>>>(h, Wx1, bx1, M1);
    k_mask<<<dim3(FF / 64, NN / 4), dim3(64, 4), 0, stream>>>(M1, Wx2, bx2, x, out1,
                                                              k2a, k2b, Lmin, Lmax);
}